// Round 16
// baseline (223.170 us; speedup 1.0000x reference)
//
#include <hip/hip_runtime.h>
#include <hip/hip_bf16.h>

#define H 768
#define NH 12
#define HD 64
#define FF 3072
#define SQ 1024
#define SKV 1024

typedef __hip_bfloat16 bf16;
typedef __attribute__((ext_vector_type(8))) short short8;   // bf16x8 fragment (guide §3)
typedef __attribute__((ext_vector_type(4))) float f32x4;
typedef __attribute__((ext_vector_type(16))) float f32x16;

__device__ inline void gload16(const void* g, void* l) {
  __builtin_amdgcn_global_load_lds((const __attribute__((address_space(1))) void*)g,
                                   (__attribute__((address_space(3))) void*)l, 16, 0, 0);
}

__device__ inline float bf2f(unsigned short u) {
  unsigned int x = ((unsigned int)u) << 16;
  return __builtin_bit_cast(float, x);
}

// packed bf16 pair: lo -> bits[15:0], hi -> bits[31:16]
__device__ inline unsigned int cvtpk(float lo, float hi) {
  unsigned int r;
  asm("v_cvt_pk_bf16_f32 %0, %1, %2" : "=v"(r) : "v"(lo), "v"(hi));
  return r;
}

// ---------------- fused pre-pass: 2x cvt_bf16 + 5x transpose-convert in one launch ----------------
__device__ inline void cvt_body(const float* __restrict__ src, bf16* __restrict__ dst, int blk) {
  int i = blk * 256 + threadIdx.x;
  float4 v = ((const float4*)src)[i];
  union { unsigned short u[4]; uint2 q; } o;
  bf16 t0 = __float2bfloat16(v.x); o.u[0] = *(unsigned short*)&t0;
  bf16 t1 = __float2bfloat16(v.y); o.u[1] = *(unsigned short*)&t1;
  bf16 t2 = __float2bfloat16(v.z); o.u[2] = *(unsigned short*)&t2;
  bf16 t3 = __float2bfloat16(v.w); o.u[3] = *(unsigned short*)&t3;
  ((uint2*)dst)[i] = o.q;
}

__device__ inline void trans_body(const float* __restrict__ src, bf16* __restrict__ dst,
                                  int Kd, int Nd, int blk, float* tile /*32*33*/) {
  int ntx = Nd >> 5;
  int n0 = (blk % ntx) << 5, k0 = (blk / ntx) << 5;
  int tx = threadIdx.x & 31, ty = threadIdx.x >> 5;  // 32 x 8
#pragma unroll
  for (int i = 0; i < 4; ++i)
    tile[(ty + i * 8) * 33 + tx] = src[(size_t)(k0 + ty + i * 8) * Nd + n0 + tx];
  __syncthreads();
#pragma unroll
  for (int i = 0; i < 4; ++i)
    dst[(size_t)(n0 + ty + i * 8) * Kd + k0 + tx] = __float2bfloat16(tile[tx * 33 + ty + i * 8]);
}

__global__ __launch_bounds__(256) void prep(
    const float* freq, const float* image, bf16* freqb, bf16* imageb,
    const float* Wq, const float* Wk, const float* Wv, const float* W1, const float* W2,
    bf16* WTq, bf16* WTk, bf16* WTv, bf16* W1T, bf16* W2T, int c1) {
  __shared__ float tile[32 * 33];
  int b = blockIdx.x;
  if (b < c1) { cvt_body(freq, freqb, b); return; }
  b -= c1;
  if (b < c1) { cvt_body(image, imageb, b); return; }
  b -= c1;
  const int TQ = (H / 32) * (H / 32);        // 576
  const int T1 = (FF / 32) * (H / 32);       // 2304
  if (b < TQ)            { trans_body(Wq, WTq, H, H, b, tile); return; }
  b -= TQ;
  if (b < TQ)            { trans_body(Wk, WTk, H, H, b, tile); return; }
  b -= TQ;
  if (b < TQ)            { trans_body(Wv, WTv, H, H, b, tile); return; }
  b -= TQ;
  if (b < T1)            { trans_body(W1, W1T, H, FF, b, tile); return; }
  b -= T1;
  trans_body(W2, W2T, FF, H, b, tile);
}

// ---------------- GEMM: C[M,N] = A[M,K] * BT[N,K]^T, 128xBN tile, BK=64 ----------------
// TH=512: 8 waves, wave grid 4x2 (wave tile 32 x BN/2).
// TH=256: 4 waves, wave grid 2x2 (wave tile 64 x BN/2) — 2x MFMA:ds_read ratio.
// EPI 2: MLP1 -> out0 bf16 [M][N], relu(x+bias0)
// EPI 3: MLP2 -> out0 bf16 [M][N], x+bias0
// EPI 4: fused QKV. Blocks [0,nkv): KV-proj (K out0, V^T out1 packed). Blocks [nkv,..): Q-proj.
template <int EPI, int BN, int TH>
__global__ __launch_bounds__(TH) void gemm_bt(
    const bf16* __restrict__ A, const bf16* __restrict__ BT,
    const float* __restrict__ bias0, const float* __restrict__ bias1,
    void* __restrict__ out0, void* __restrict__ out1, int M, int N, int K,
    const bf16* __restrict__ Aq, const bf16* __restrict__ BTq,
    const float* __restrict__ biasq, void* __restrict__ outq) {
  constexpr int JF = BN / 32;        // col-frags per wave (wc spans BN/2)
  constexpr int MI = (TH == 512) ? 2 : 4;     // m-frags per wave
  constexpr int WROW = (TH == 512) ? 32 : 64; // wave row span
  constexpr int AI = 1024 / TH;      // A-stage iterations (1024 slots of 16B)
  constexpr int BI = BN * 8 / TH;    // B-stage iterations
  __shared__ __align__(16) bf16 lA[128 * 64];
  __shared__ __align__(16) bf16 lB[BN * 64];
  const int t = threadIdx.x;
  const int lane = t & 63, w = t >> 6;
  const int wr = w >> 1, wc = w & 1;
  const int nwg = gridDim.x;
  int bid = blockIdx.x;
  int logical = ((nwg & 7) == 0) ? ((bid & 7) * (nwg >> 3) + (bid >> 3)) : bid;

  bool isq = false;
  int lg = logical;
  const bf16* Ause = A;
  const bf16* BTuse = BT;
  int nt = N / BN;
  if (EPI == 4) {
    const int nkv = (M >> 7) * (2 * H / BN);   // 768
    if (logical >= nkv) {
      isq = true; lg = logical - nkv;
      Ause = Aq; BTuse = BTq; nt = H / BN;
    }
  }
  const int m0 = (lg / nt) << 7;
  const int n0 = (lg % nt) * BN;

  const f32x4 fz = {0.f, 0.f, 0.f, 0.f};
  f32x4 acc[MI][JF];
#pragma unroll
  for (int i = 0; i < MI; ++i)
#pragma unroll
    for (int j = 0; j < JF; ++j) acc[i][j] = fz;

  for (int kt = 0; kt < K; kt += 64) {
    // A tile: 1024 slots of 16B
#pragma unroll
    for (int i = 0; i < AI; ++i) {
      int idx = i * TH + t;
      int row = idx >> 3;
      int chunk = (idx & 7) ^ (row & 7);
      gload16(Ause + (size_t)(m0 + row) * K + kt + chunk * 8, lA + (size_t)(i * TH + w * 64) * 8);
    }
    // B tile: BN*8 slots
#pragma unroll
    for (int i = 0; i < BI; ++i) {
      int idx = i * TH + t;
      int row = idx >> 3;
      int chunk = (idx & 7) ^ (row & 7);
      gload16(BTuse + (size_t)(n0 + row) * K + kt + chunk * 8, lB + (size_t)(i * TH + w * 64) * 8);
    }
    __syncthreads();

    short8 af[2][MI], bfv[2][JF];
#pragma unroll
    for (int s = 0; s < 2; ++s) {
#pragma unroll
      for (int i = 0; i < MI; ++i) {
        int ra = wr * WROW + i * 16 + (lane & 15);
        int ca = (s * 4 + (lane >> 4)) ^ (ra & 7);
        af[s][i] = *(const short8*)&lA[ra * 64 + ca * 8];
      }
#pragma unroll
      for (int j = 0; j < JF; ++j) {
        int rb = wc * (BN / 2) + j * 16 + (lane & 15);
        int cb = (s * 4 + (lane >> 4)) ^ (rb & 7);
        bfv[s][j] = *(const short8*)&lB[rb * 64 + cb * 8];
      }
    }
#pragma unroll
    for (int s = 0; s < 2; ++s)
#pragma unroll
      for (int i = 0; i < MI; ++i)
#pragma unroll
        for (int j = 0; j < JF; ++j)
          acc[i][j] = __builtin_amdgcn_mfma_f32_16x16x32_bf16(af[s][i], bfv[s][j], acc[i][j], 0, 0, 0);
    __syncthreads();
  }

  // epilogue (C/D layout: row=(lane>>4)*4+r, col=lane&15 — m89/m91 verified)
#pragma unroll
  for (int i = 0; i < MI; ++i) {
    int mbase = m0 + wr * WROW + i * 16 + ((lane >> 4) << 2);
    int mb = mbase & 1023, bidx = mbase >> 10;
#pragma unroll
    for (int j = 0; j < JF; ++j) {
      int n = n0 + wc * (BN / 2) + j * 16 + (lane & 15);
      if (EPI == 4) {
        if (isq) {
          int hlin = bidx * NH + (n >> 6);
#pragma unroll
          for (int r = 0; r < 4; ++r) {
            float v = (acc[i][j][r] + biasq[n]) * 0.180336880f;  // 0.125*log2e folded
            ((bf16*)outq)[((size_t)hlin * SQ + (mb + r)) * HD + (n & 63)] = __float2bfloat16(v);
          }
        } else {
          int sel = (n >= H);
          int nn = n - (sel ? H : 0);
          int hlin = bidx * NH + (nn >> 6);
          float bsv = (sel ? bias1 : bias0)[nn];
          float v0 = acc[i][j][0] + bsv, v1 = acc[i][j][1] + bsv;
          float v2 = acc[i][j][2] + bsv, v3 = acc[i][j][3] + bsv;
          if (!sel) {
            bf16* kp = (bf16*)out0 + ((size_t)hlin * SKV + mb) * HD + (nn & 63);
            kp[0 * HD] = __float2bfloat16(v0);
            kp[1 * HD] = __float2bfloat16(v1);
            kp[2 * HD] = __float2bfloat16(v2);
            kp[3 * HD] = __float2bfloat16(v3);
          } else {
            // V^T: 4 m-contiguous values -> one 8B store
            uint2 u;
            u.x = cvtpk(v0, v1);
            u.y = cvtpk(v2, v3);
            *(uint2*)((bf16*)out1 + ((size_t)hlin * HD + (nn & 63)) * SKV + mb) = u;
          }
        }
      } else {
#pragma unroll
        for (int r = 0; r < 4; ++r) {
          int m = mbase + r;
          float v = acc[i][j][r] + bias0[n];
          if (EPI == 2) v = fmaxf(v, 0.f);
          ((bf16*)out0)[(size_t)m * N + n] = __float2bfloat16(v);
        }
      }
    }
  }
}

// ---------------- flash attention: 32x32 MFMA, in-register softmax, q-group x kv-half waves ----------
// 1 block = (head, 128 q-rows), 8 waves = 4 q-groups x 2 kv-halves. Q pre-scaled by 0.125*log2e.
// No-max softmax: P = exp2(S) (scores O(3) in log2 domain; constant cancels in O/l).
// Swapped QK^T (r6-verified): sc = mfma(K_rows, Q) -> lane holds P[q=l31][16 kv of its half].
// Each wave covers kv = 32h..32h+31 of every tile: half the K/V fragment reads of full-kv waves;
// P fully in-register via cvtpk+permlane32_swap (r6 recipe, pa k4global in {2h,2h+1});
// l accumulated in-register (no ones-MFMA). Partner waves (h=0/1) combine O and l through the
// dead K/V LDS buffers after the loop (r7-verified epilogue). Q loaded direct from global.
__global__ __launch_bounds__(512) void attn_fwd(
    const bf16* __restrict__ Q,   // [B*NH][SQ][HD] (pre-scaled)
    const bf16* __restrict__ Kg_, // [B*NH][SKV][HD]
    const bf16* __restrict__ VT,  // [B*NH][HD][SKV]
    bf16* __restrict__ ctx, int nblk) {  // [B][SQ][H] bf16
  __shared__ __align__(16) bf16 Kb[2][64 * 64];  // 8KB per buf
  __shared__ __align__(16) bf16 Vb[2][64 * 64];
  __shared__ float Lsum[4][32];

  const int t = threadIdx.x, lane = t & 63, w = t >> 6;
  const int hi = lane >> 5, l31 = lane & 31;
  const int qg = w >> 1, h = w & 1;   // q-group 0..3, kv-half 0..1
  int bid = blockIdx.x;
  int logical = ((nblk & 7) == 0) ? (bid & 7) * (nblk >> 3) + (bid >> 3) : bid;
  const int hl = logical >> 3;          // SQ/128 = 8 q-blocks per head
  const int q0 = (logical & 7) << 7;
  const bf16* Qg = Q + ((size_t)hl * SQ + q0) * HD;
  const bf16* Kg = Kg_ + (size_t)hl * SKV * HD;
  const bf16* Vg = VT + (size_t)hl * HD * SKV;

  // Q fragments direct from global (B-operand of swapped QK^T): row q = qg*32+l31, k=d
  short8 aq[4];
  {
    const bf16* qp = Qg + (size_t)(qg * 32 + l31) * HD;
#pragma unroll
    for (int ks = 0; ks < 4; ++ks)
      aq[ks] = *(const short8*)(qp + (ks * 2 + hi) * 8);
  }

  // prologue: stage K0, V0 (512 slots each, 1 per thread; swizzled source / linear dest, G21)
  {
    int row = t >> 3, chunk = (t & 7) ^ (row & 7);
    gload16(Kg + (size_t)row * HD + chunk * 8, (char*)&Kb[0][0] + (size_t)t * 16);
    gload16(Vg + (size_t)row * SKV + chunk * 8, (char*)&Vb[0][0] + (size_t)t * 16);
  }
  __syncthreads();

  f32x16 oa0, oa1;
#pragma unroll
  for (int r = 0; r < 16; ++r) { oa0[r] = 0.f; oa1[r] = 0.f; }
  float lacc = 0.f;

#pragma unroll 2
  for (int i = 0; i < 16; ++i) {
    const int buf = i & 1;
    if (i < 15) {  // prefetch next K/V tile into buf^1 (in flight across the compute)
      int kvn = (i + 1) << 6;
      int row = t >> 3, chunk = (t & 7) ^ (row & 7);
      gload16(Kg + (size_t)(kvn + row) * HD + chunk * 8, (char*)&Kb[buf ^ 1][0] + (size_t)t * 16);
      gload16(Vg + (size_t)row * SKV + kvn + chunk * 8, (char*)&Vb[buf ^ 1][0] + (size_t)t * 16);
    }

    // S^T half = mfma(K[kv=32h..32h+31], Q): sc[r] = S[q=l31][kv=32h+(r&3)+8*(r>>2)+4*hi]
    f32x16 sc;
#pragma unroll
    for (int r = 0; r < 16; ++r) sc[r] = 0.f;
    __builtin_amdgcn_s_setprio(1);
#pragma unroll
    for (int ks = 0; ks < 4; ++ks) {
      int c0 = ks * 2 + hi;
      int r0 = h * 32 + l31;
      short8 kf = *(const short8*)&Kb[buf][r0 * 64 + ((c0 ^ (r0 & 7)) * 8)];
      sc = __builtin_amdgcn_mfma_f32_32x32x16_bf16(kf, aq[ks], sc, 0, 0, 0);
    }
    __builtin_amdgcn_s_setprio(0);

    // P = exp2(S) in-register; accumulate partial l
#pragma unroll
    for (int r = 0; r < 16; ++r) { sc[r] = exp2f(sc[r]); lacc += sc[r]; }

    // PA fragments for own kv-half: pa[k4l], k4global = 2h + k4l (r6-verified recipe)
    short8 pa[2];
#pragma unroll
    for (int k4 = 0; k4 < 2; ++k4) {
      const int base = k4 * 8;
      unsigned int p0 = cvtpk(sc[base + 0], sc[base + 1]);
      unsigned int p1 = cvtpk(sc[base + 2], sc[base + 3]);
      unsigned int qq0 = cvtpk(sc[base + 4], sc[base + 5]);
      unsigned int qq1 = cvtpk(sc[base + 6], sc[base + 7]);
      asm volatile("v_permlane32_swap_b32 %0, %1" : "+v"(p0), "+v"(qq0));
      asm volatile("v_permlane32_swap_b32 %0, %1" : "+v"(p1), "+v"(qq1));
      union { unsigned int u[4]; short8 s8; } pu;
      pu.u[0] = p0; pu.u[1] = p1; pu.u[2] = qq0; pu.u[3] = qq1;
      pa[k4] = pu.s8;
    }

    // O += P V over own kv-half (V^T tile: rows d, cols kv; cc = 4h + 2*k4l + hi)
    __builtin_amdgcn_s_setprio(1);
#pragma unroll
    for (int k4 = 0; k4 < 2; ++k4) {
      int cc = 4 * h + k4 * 2 + hi;
      int r0 = l31;
      short8 vf0 = *(const short8*)&Vb[buf][r0 * 64 + ((cc ^ (r0 & 7)) * 8)];
      oa0 = __builtin_amdgcn_mfma_f32_32x32x16_bf16(pa[k4], vf0, oa0, 0, 0, 0);
      int r1 = 32 + l31;
      short8 vf1 = *(const short8*)&Vb[buf][r1 * 64 + ((cc ^ (r1 & 7)) * 8)];
      oa1 = __builtin_amdgcn_mfma_f32_32x32x16_bf16(pa[k4], vf1, oa1, 0, 0, 0);
    }
    __builtin_amdgcn_s_setprio(0);

    __syncthreads();  // all waves done with buf; prefetch into buf^1 drained here
  }

  // l for own half, q=l31: own lane covers kv-slots with bit2==hi; partner lane the rest
  float lt = lacc + __shfl_xor(lacc, 32);

  // combine kv-halves across partner waves via dead K/V buffers (r7-verified epilogue)
  float* Cg = (qg < 2) ? ((float*)&Kb[0][0] + qg * 2048)
                       : ((float*)&Vb[0][0] + (qg - 2) * 2048);
  if (h == 1) {
#pragma unroll
    for (int r = 0; r < 16; ++r) {
      int ro = (r & 3) + 8 * (r >> 2) + 4 * hi;
      Cg[ro * 64 + l31] = oa0[r];
      Cg[ro * 64 + 32 + l31] = oa1[r];
    }
    if (hi == 0) Lsum[qg][l31] = lt;
  }
  __syncthreads();
  if (h == 0) {
    float rlq = 1.0f / (lt + Lsum[qg][l31]);
    const int b = hl / NH, hh = hl % NH;
    bf16* outp = ctx + ((size_t)b * SQ + q0 + qg * 32) * H + hh * HD;
#pragma unroll
    for (int r = 0; r < 16; ++r) {
      int qo = (r & 3) + 8 * (r >> 2) + 4 * hi;
      float rv = __shfl(rlq, qo);
      float v0 = oa0[r] + Cg[qo * 64 + l31];
      float v1 = oa1[r] + Cg[qo * 64 + 32 + l31];
      bf16* rowp = outp + (size_t)qo * H;
      rowp[l31]      = __float2bfloat16(v0 * rv);
      rowp[32 + l31] = __float2bfloat16(v1 * rv);
    }
  }
}

// ---------------- residual + post-LN: o = res + LN(x)*g + beta (x,res bf16; 192 thr) ----------------
__global__ __launch_bounds__(192) void ln_res(
    const bf16* __restrict__ x, const bf16* __restrict__ res,
    const float* __restrict__ g, const float* __restrict__ beta,
    float* __restrict__ o32, bf16* __restrict__ ob) {
  const int row = blockIdx.x;
  const int t = threadIdx.x;
  float v[4];
  float s = 0.f, s2 = 0.f;
  ushort4 xv = ((const ushort4*)(x + (size_t)row * H))[t];
  v[0] = bf2f(xv.x); v[1] = bf2f(xv.y); v[2] = bf2f(xv.z); v[3] = bf2f(xv.w);
#pragma unroll
  for (int k = 0; k < 4; ++k) { s += v[k]; s2 += v[k] * v[k]; }
#pragma unroll
  for (int off = 32; off > 0; off >>= 1) {
    s += __shfl_down(s, off);
    s2 += __shfl_down(s2, off);
  }
  __shared__ float red[8];
  if ((t & 63) == 0) { red[t >> 6] = s; red[4 + (t >> 6)] = s2; }
  __syncthreads();
  float st = red[0] + red[1] + red[2];
  float s2t = red[4] + red[5] + red[6];
  float mean = st * (1.f / 768.f);
  float var = s2t * (1.f / 768.f) - mean * mean;
  float rs = rsqrtf(var + 1e-5f);
  {
    ushort4 rv4 = ((const ushort4*)(res + (size_t)row * H))[t];
    float4 gv = ((const float4*)g)[t];
    float4 bv = ((const float4*)beta)[t];
    float4 o;
    o.x = bf2f(rv4.x) + (v[0] - mean) * rs * gv.x + bv.x;
    o.y = bf2f(rv4.y) + (v[1] - mean) * rs * gv.y + bv.y;
    o.z = bf2f(rv4.z) + (v[2] - mean) * rs * gv.z + bv.z;
    o.w = bf2f(rv4.w) + (v[3] - mean) * rs * gv.w + bv.w;
    if (o32) ((float4*)(o32 + (size_t)row * H))[t] = o;
    if (ob) {
      uint2 q;
      q.x = cvtpk(o.x, o.y);
      q.y = cvtpk(o.z, o.w);
      ((uint2*)(ob + (size_t)row * H))[t] = q;
    }
  }
}

extern "C" void kernel_launch(void* const* d_in, const int* in_sizes, int n_in,
                              void* d_out, int out_size, void* d_ws, size_t ws_size,
                              hipStream_t stream) {
  const float* freq  = (const float*)d_in[0];
  const float* image = (const float*)d_in[1];
  const float* Wq = (const float*)d_in[2];
  const float* bq = (const float*)d_in[3];
  const float* Wk = (const float*)d_in[4];
  const float* bk = (const float*)d_in[5];
  const float* Wv = (const float*)d_in[6];
  const float* bv = (const float*)d_in[7];
  const float* g1 = (const float*)d_in[8];
  const float* be1 = (const float*)d_in[9];
  const float* g2 = (const float*)d_in[10];
  const float* be2 = (const float*)d_in[11];
  const float* W1 = (const float*)d_in[12];
  const float* b1 = (const float*)d_in[13];
  const float* W2 = (const float*)d_in[14];
  const float* b2 = (const float*)d_in[15];

  const int Bc = in_sizes[0] / (SQ * H);  // 8
  const int M = Bc * SQ;                  // 8192

  char* p = (char*)d_ws;
  bf16* W1T = (bf16*)p;  p += (size_t)FF * H * 2;
  bf16* W2T = (bf16*)p;  p += (size_t)H * FF * 2;
  bf16* ctxb = (bf16*)p; p += (size_t)M * H * 2;   // attn out (bf16); reused for mlp2 out
  bf16* hb = (bf16*)p;   p += (size_t)M * H * 2;   // h = freq + LN(ctx) in bf16 (residual + MLP1 A)
  char* U = p;  // union region
  bf16* freqb = (bf16*)U;
  bf16* imageb = (bf16*)(U + (size_t)M * H * 2);
  bf16* WTq   = (bf16*)(U + (size_t)2 * M * H * 2);
  bf16* WTkv  = (bf16*)(U + (size_t)2 * M * H * 2 + (size_t)H * H * 2);
  bf16* Qb    = (bf16*)(U + (size_t)2 * M * H * 2 + (size_t)3 * H * H * 2);
  bf16* Kbuf  = (bf16*)((char*)Qb + (size_t)M * H * 2);
  bf16* VTb   = (bf16*)((char*)Kbuf + (size_t)M * H * 2);
  bf16* mlp1  = (bf16*)U;    // reused after attention+ln1 consumed freqb/Q/K/VT
  bf16* mlp2b = ctxb;        // reused after first ln_res consumed ctxb

  // fused pre-pass: c1 blocks per cvt, then 3x576 + 2x2304 transpose tiles
  int c1 = M * H / 1024;
  int nprep = 2 * c1 + 3 * ((H / 32) * (H / 32)) + (FF / 32) * (H / 32) + (H / 32) * (FF / 32);
  prep<<<nprep, 256, 0, stream>>>(freq, image, freqb, imageb,
                                  Wq, Wk, Wv, W1, W2,
                                  WTq, WTkv, WTkv + (size_t)H * H, W1T, W2T, c1);

  // fused QKV projection: 768 KV-blocks (BN=128 over N=1536) + 384 Q-blocks (BN=128 over N=768)
  int nqkv = (M / 128) * (2 * H / 128) + (M / 128) * (H / 128);  // 1152, %8==0
  gemm_bt<4, 128, 512><<<nqkv, 512, 0, stream>>>(imageb, WTkv, bk, bv, Kbuf, VTb, M, 2 * H, H,
                                                 freqb, WTq, bq, Qb);
  int nblk = Bc * NH * (SQ / 128);
  attn_fwd<<<nblk, 512, 0, stream>>>(Qb, Kbuf, VTb, ctxb, nblk);
  ln_res<<<M, 192, 0, stream>>>(ctxb, freqb, g1, be1, nullptr, hb);
  gemm_bt<2, 128, 512><<<(M / 128) * (FF / 128), 512, 0, stream>>>(hb, W1T, b1, nullptr, mlp1, nullptr,
                                                                   M, FF, H, nullptr, nullptr, nullptr, nullptr);
  // MLP2: 4-wave blocks (wave tile 64x32) — 2x MFMA:ds_read ratio for the thin-N K=3072 GEMM
  gemm_bt<3, 64, 256><<<(M / 128) * (H / 64), 256, 0, stream>>>(mlp1, W2T, b2, nullptr, mlp2b, nullptr,
                                                                M, H, FF, nullptr, nullptr, nullptr, nullptr);
  ln_res<<<M, 192, 0, stream>>>(mlp2b, hb, g2, be2, (float*)d_out, nullptr);
}

// Round 17
// 216.560 us; speedup vs baseline: 1.0305x; 1.0305x over previous
//
#include <hip/hip_runtime.h>
#include <hip/hip_bf16.h>

#define H 768
#define NH 12
#define HD 64
#define FF 3072
#define SQ 1024
#define SKV 1024

typedef __hip_bfloat16 bf16;
typedef __attribute__((ext_vector_type(8))) short short8;   // bf16x8 fragment (guide §3)
typedef __attribute__((ext_vector_type(4))) float f32x4;
typedef __attribute__((ext_vector_type(16))) float f32x16;

__device__ inline void gload16(const void* g, void* l) {
  __builtin_amdgcn_global_load_lds((const __attribute__((address_space(1))) void*)g,
                                   (__attribute__((address_space(3))) void*)l, 16, 0, 0);
}

__device__ inline float bf2f(unsigned short u) {
  unsigned int x = ((unsigned int)u) << 16;
  return __builtin_bit_cast(float, x);
}

// packed bf16 pair: lo -> bits[15:0], hi -> bits[31:16]
__device__ inline unsigned int cvtpk(float lo, float hi) {
  unsigned int r;
  asm("v_cvt_pk_bf16_f32 %0, %1, %2" : "=v"(r) : "v"(lo), "v"(hi));
  return r;
}

// ---------------- fused pre-pass: 2x cvt_bf16 + 5x transpose-convert in one launch ----------------
__device__ inline void cvt_body(const float* __restrict__ src, bf16* __restrict__ dst, int blk) {
  int i = blk * 256 + threadIdx.x;
  float4 v = ((const float4*)src)[i];
  union { unsigned short u[4]; uint2 q; } o;
  bf16 t0 = __float2bfloat16(v.x); o.u[0] = *(unsigned short*)&t0;
  bf16 t1 = __float2bfloat16(v.y); o.u[1] = *(unsigned short*)&t1;
  bf16 t2 = __float2bfloat16(v.z); o.u[2] = *(unsigned short*)&t2;
  bf16 t3 = __float2bfloat16(v.w); o.u[3] = *(unsigned short*)&t3;
  ((uint2*)dst)[i] = o.q;
}

__device__ inline void trans_body(const float* __restrict__ src, bf16* __restrict__ dst,
                                  int Kd, int Nd, int blk, float* tile /*32*33*/) {
  int ntx = Nd >> 5;
  int n0 = (blk % ntx) << 5, k0 = (blk / ntx) << 5;
  int tx = threadIdx.x & 31, ty = threadIdx.x >> 5;  // 32 x 8
#pragma unroll
  for (int i = 0; i < 4; ++i)
    tile[(ty + i * 8) * 33 + tx] = src[(size_t)(k0 + ty + i * 8) * Nd + n0 + tx];
  __syncthreads();
#pragma unroll
  for (int i = 0; i < 4; ++i)
    dst[(size_t)(n0 + ty + i * 8) * Kd + k0 + tx] = __float2bfloat16(tile[tx * 33 + ty + i * 8]);
}

__global__ __launch_bounds__(256) void prep(
    const float* freq, const float* image, bf16* freqb, bf16* imageb,
    const float* Wq, const float* Wk, const float* Wv, const float* W1, const float* W2,
    bf16* WTq, bf16* WTk, bf16* WTv, bf16* W1T, bf16* W2T, int c1) {
  __shared__ float tile[32 * 33];
  int b = blockIdx.x;
  if (b < c1) { cvt_body(freq, freqb, b); return; }
  b -= c1;
  if (b < c1) { cvt_body(image, imageb, b); return; }
  b -= c1;
  const int TQ = (H / 32) * (H / 32);        // 576
  const int T1 = (FF / 32) * (H / 32);       // 2304
  if (b < TQ)            { trans_body(Wq, WTq, H, H, b, tile); return; }
  b -= TQ;
  if (b < TQ)            { trans_body(Wk, WTk, H, H, b, tile); return; }
  b -= TQ;
  if (b < TQ)            { trans_body(Wv, WTv, H, H, b, tile); return; }
  b -= TQ;
  if (b < T1)            { trans_body(W1, W1T, H, FF, b, tile); return; }
  b -= T1;
  trans_body(W2, W2T, FF, H, b, tile);
}

// ---------------- GEMM: C[M,N] = A[M,K] * BT[N,K]^T, 128xBN tile, BK=64 ----------------
// TH=512: 8 waves, wave grid 4x2 (wave tile 32 x BN/2).
// EPI 2: MLP1 -> out0 bf16 [M][N], relu(x+bias0)
// EPI 3: MLP2 -> out0 bf16 [M][N], x+bias0
// EPI 4: fused QKV. Blocks [0,nkv): KV-proj (K out0, V^T out1 packed). Blocks [nkv,..): Q-proj.
template <int EPI, int BN, int TH>
__global__ __launch_bounds__(TH) void gemm_bt(
    const bf16* __restrict__ A, const bf16* __restrict__ BT,
    const float* __restrict__ bias0, const float* __restrict__ bias1,
    void* __restrict__ out0, void* __restrict__ out1, int M, int N, int K,
    const bf16* __restrict__ Aq, const bf16* __restrict__ BTq,
    const float* __restrict__ biasq, void* __restrict__ outq) {
  constexpr int JF = BN / 32;        // col-frags per wave (wc spans BN/2)
  constexpr int MI = (TH == 512) ? 2 : 4;     // m-frags per wave
  constexpr int WROW = (TH == 512) ? 32 : 64; // wave row span
  constexpr int AI = 1024 / TH;      // A-stage iterations (1024 slots of 16B)
  constexpr int BI = BN * 8 / TH;    // B-stage iterations
  __shared__ __align__(16) bf16 lA[128 * 64];
  __shared__ __align__(16) bf16 lB[BN * 64];
  const int t = threadIdx.x;
  const int lane = t & 63, w = t >> 6;
  const int wr = w >> 1, wc = w & 1;
  const int nwg = gridDim.x;
  int bid = blockIdx.x;
  int logical = ((nwg & 7) == 0) ? ((bid & 7) * (nwg >> 3) + (bid >> 3)) : bid;

  bool isq = false;
  int lg = logical;
  const bf16* Ause = A;
  const bf16* BTuse = BT;
  int nt = N / BN;
  if (EPI == 4) {
    const int nkv = (M >> 7) * (2 * H / BN);   // 768
    if (logical >= nkv) {
      isq = true; lg = logical - nkv;
      Ause = Aq; BTuse = BTq; nt = H / BN;
    }
  }
  const int m0 = (lg / nt) << 7;
  const int n0 = (lg % nt) * BN;

  const f32x4 fz = {0.f, 0.f, 0.f, 0.f};
  f32x4 acc[MI][JF];
#pragma unroll
  for (int i = 0; i < MI; ++i)
#pragma unroll
    for (int j = 0; j < JF; ++j) acc[i][j] = fz;

  for (int kt = 0; kt < K; kt += 64) {
    // A tile: 1024 slots of 16B
#pragma unroll
    for (int i = 0; i < AI; ++i) {
      int idx = i * TH + t;
      int row = idx >> 3;
      int chunk = (idx & 7) ^ (row & 7);
      gload16(Ause + (size_t)(m0 + row) * K + kt + chunk * 8, lA + (size_t)(i * TH + w * 64) * 8);
    }
    // B tile: BN*8 slots
#pragma unroll
    for (int i = 0; i < BI; ++i) {
      int idx = i * TH + t;
      int row = idx >> 3;
      int chunk = (idx & 7) ^ (row & 7);
      gload16(BTuse + (size_t)(n0 + row) * K + kt + chunk * 8, lB + (size_t)(i * TH + w * 64) * 8);
    }
    __syncthreads();

    short8 af[2][MI], bfv[2][JF];
#pragma unroll
    for (int s = 0; s < 2; ++s) {
#pragma unroll
      for (int i = 0; i < MI; ++i) {
        int ra = wr * WROW + i * 16 + (lane & 15);
        int ca = (s * 4 + (lane >> 4)) ^ (ra & 7);
        af[s][i] = *(const short8*)&lA[ra * 64 + ca * 8];
      }
#pragma unroll
      for (int j = 0; j < JF; ++j) {
        int rb = wc * (BN / 2) + j * 16 + (lane & 15);
        int cb = (s * 4 + (lane >> 4)) ^ (rb & 7);
        bfv[s][j] = *(const short8*)&lB[rb * 64 + cb * 8];
      }
    }
#pragma unroll
    for (int s = 0; s < 2; ++s)
#pragma unroll
      for (int i = 0; i < MI; ++i)
#pragma unroll
        for (int j = 0; j < JF; ++j)
          acc[i][j] = __builtin_amdgcn_mfma_f32_16x16x32_bf16(af[s][i], bfv[s][j], acc[i][j], 0, 0, 0);
    __syncthreads();
  }

  // epilogue (C/D layout: row=(lane>>4)*4+r, col=lane&15 — m89/m91 verified)
#pragma unroll
  for (int i = 0; i < MI; ++i) {
    int mbase = m0 + wr * WROW + i * 16 + ((lane >> 4) << 2);
    int mb = mbase & 1023, bidx = mbase >> 10;
#pragma unroll
    for (int j = 0; j < JF; ++j) {
      int n = n0 + wc * (BN / 2) + j * 16 + (lane & 15);
      if (EPI == 4) {
        if (isq) {
          int hlin = bidx * NH + (n >> 6);
#pragma unroll
          for (int r = 0; r < 4; ++r) {
            float v = (acc[i][j][r] + biasq[n]) * 0.180336880f;  // 0.125*log2e folded
            ((bf16*)outq)[((size_t)hlin * SQ + (mb + r)) * HD + (n & 63)] = __float2bfloat16(v);
          }
        } else {
          int sel = (n >= H);
          int nn = n - (sel ? H : 0);
          int hlin = bidx * NH + (nn >> 6);
          float bsv = (sel ? bias1 : bias0)[nn];
          float v0 = acc[i][j][0] + bsv, v1 = acc[i][j][1] + bsv;
          float v2 = acc[i][j][2] + bsv, v3 = acc[i][j][3] + bsv;
          if (!sel) {
            bf16* kp = (bf16*)out0 + ((size_t)hlin * SKV + mb) * HD + (nn & 63);
            kp[0 * HD] = __float2bfloat16(v0);
            kp[1 * HD] = __float2bfloat16(v1);
            kp[2 * HD] = __float2bfloat16(v2);
            kp[3 * HD] = __float2bfloat16(v3);
          } else {
            // V^T: 4 m-contiguous values -> one 8B store
            uint2 u;
            u.x = cvtpk(v0, v1);
            u.y = cvtpk(v2, v3);
            *(uint2*)((bf16*)out1 + ((size_t)hlin * HD + (nn & 63)) * SKV + mb) = u;
          }
        }
      } else {
#pragma unroll
        for (int r = 0; r < 4; ++r) {
          int m = mbase + r;
          float v = acc[i][j][r] + bias0[n];
          if (EPI == 2) v = fmaxf(v, 0.f);
          ((bf16*)out0)[(size_t)m * N + n] = __float2bfloat16(v);
        }
      }
    }
  }
}

// ---------------- flash attention: 32x32 MFMA, in-register softmax, q-group x kv-half waves ----------
// 1 block = (head, 128 q-rows), 8 waves = 4 q-groups x 2 kv-halves. Q pre-scaled by 0.125*log2e.
// No-max softmax: P = exp2(S) (scores O(3) in log2 domain; constant cancels in O/l).
// Swapped QK^T (r6-verified): sc = mfma(K_rows, Q) -> lane holds P[q=l31][16 kv of its half].
// Each wave covers kv = 32h..32h+31 of every tile: half the K/V fragment reads of full-kv waves;
// P fully in-register via cvtpk+permlane32_swap (r6 recipe, pa k4global in {2h,2h+1});
// l accumulated in-register (no ones-MFMA). Partner waves (h=0/1) combine O and l through the
// dead K/V LDS buffers after the loop (r7-verified epilogue). Q loaded direct from global.
__global__ __launch_bounds__(512) void attn_fwd(
    const bf16* __restrict__ Q,   // [B*NH][SQ][HD] (pre-scaled)
    const bf16* __restrict__ Kg_, // [B*NH][SKV][HD]
    const bf16* __restrict__ VT,  // [B*NH][HD][SKV]
    bf16* __restrict__ ctx, int nblk) {  // [B][SQ][H] bf16
  __shared__ __align__(16) bf16 Kb[2][64 * 64];  // 8KB per buf
  __shared__ __align__(16) bf16 Vb[2][64 * 64];
  __shared__ float Lsum[4][32];

  const int t = threadIdx.x, lane = t & 63, w = t >> 6;
  const int hi = lane >> 5, l31 = lane & 31;
  const int qg = w >> 1, h = w & 1;   // q-group 0..3, kv-half 0..1
  int bid = blockIdx.x;
  int logical = ((nblk & 7) == 0) ? (bid & 7) * (nblk >> 3) + (bid >> 3) : bid;
  const int hl = logical >> 3;          // SQ/128 = 8 q-blocks per head
  const int q0 = (logical & 7) << 7;
  const bf16* Qg = Q + ((size_t)hl * SQ + q0) * HD;
  const bf16* Kg = Kg_ + (size_t)hl * SKV * HD;
  const bf16* Vg = VT + (size_t)hl * HD * SKV;

  // Q fragments direct from global (B-operand of swapped QK^T): row q = qg*32+l31, k=d
  short8 aq[4];
  {
    const bf16* qp = Qg + (size_t)(qg * 32 + l31) * HD;
#pragma unroll
    for (int ks = 0; ks < 4; ++ks)
      aq[ks] = *(const short8*)(qp + (ks * 2 + hi) * 8);
  }

  // prologue: stage K0, V0 (512 slots each, 1 per thread; swizzled source / linear dest, G21)
  {
    int row = t >> 3, chunk = (t & 7) ^ (row & 7);
    gload16(Kg + (size_t)row * HD + chunk * 8, (char*)&Kb[0][0] + (size_t)t * 16);
    gload16(Vg + (size_t)row * SKV + chunk * 8, (char*)&Vb[0][0] + (size_t)t * 16);
  }
  __syncthreads();

  f32x16 oa0, oa1;
#pragma unroll
  for (int r = 0; r < 16; ++r) { oa0[r] = 0.f; oa1[r] = 0.f; }
  float lacc = 0.f;

#pragma unroll 2
  for (int i = 0; i < 16; ++i) {
    const int buf = i & 1;
    if (i < 15) {  // prefetch next K/V tile into buf^1 (in flight across the compute)
      int kvn = (i + 1) << 6;
      int row = t >> 3, chunk = (t & 7) ^ (row & 7);
      gload16(Kg + (size_t)(kvn + row) * HD + chunk * 8, (char*)&Kb[buf ^ 1][0] + (size_t)t * 16);
      gload16(Vg + (size_t)row * SKV + kvn + chunk * 8, (char*)&Vb[buf ^ 1][0] + (size_t)t * 16);
    }

    // S^T half = mfma(K[kv=32h..32h+31], Q): sc[r] = S[q=l31][kv=32h+(r&3)+8*(r>>2)+4*hi]
    f32x16 sc;
#pragma unroll
    for (int r = 0; r < 16; ++r) sc[r] = 0.f;
    __builtin_amdgcn_s_setprio(1);
#pragma unroll
    for (int ks = 0; ks < 4; ++ks) {
      int c0 = ks * 2 + hi;
      int r0 = h * 32 + l31;
      short8 kf = *(const short8*)&Kb[buf][r0 * 64 + ((c0 ^ (r0 & 7)) * 8)];
      sc = __builtin_amdgcn_mfma_f32_32x32x16_bf16(kf, aq[ks], sc, 0, 0, 0);
    }
    __builtin_amdgcn_s_setprio(0);

    // P = exp2(S) in-register; accumulate partial l
#pragma unroll
    for (int r = 0; r < 16; ++r) { sc[r] = exp2f(sc[r]); lacc += sc[r]; }

    // PA fragments for own kv-half: pa[k4l], k4global = 2h + k4l (r6-verified recipe)
    short8 pa[2];
#pragma unroll
    for (int k4 = 0; k4 < 2; ++k4) {
      const int base = k4 * 8;
      unsigned int p0 = cvtpk(sc[base + 0], sc[base + 1]);
      unsigned int p1 = cvtpk(sc[base + 2], sc[base + 3]);
      unsigned int qq0 = cvtpk(sc[base + 4], sc[base + 5]);
      unsigned int qq1 = cvtpk(sc[base + 6], sc[base + 7]);
      asm volatile("v_permlane32_swap_b32 %0, %1" : "+v"(p0), "+v"(qq0));
      asm volatile("v_permlane32_swap_b32 %0, %1" : "+v"(p1), "+v"(qq1));
      union { unsigned int u[4]; short8 s8; } pu;
      pu.u[0] = p0; pu.u[1] = p1; pu.u[2] = qq0; pu.u[3] = qq1;
      pa[k4] = pu.s8;
    }

    // O += P V over own kv-half (V^T tile: rows d, cols kv; cc = 4h + 2*k4l + hi)
    __builtin_amdgcn_s_setprio(1);
#pragma unroll
    for (int k4 = 0; k4 < 2; ++k4) {
      int cc = 4 * h + k4 * 2 + hi;
      int r0 = l31;
      short8 vf0 = *(const short8*)&Vb[buf][r0 * 64 + ((cc ^ (r0 & 7)) * 8)];
      oa0 = __builtin_amdgcn_mfma_f32_32x32x16_bf16(pa[k4], vf0, oa0, 0, 0, 0);
      int r1 = 32 + l31;
      short8 vf1 = *(const short8*)&Vb[buf][r1 * 64 + ((cc ^ (r1 & 7)) * 8)];
      oa1 = __builtin_amdgcn_mfma_f32_32x32x16_bf16(pa[k4], vf1, oa1, 0, 0, 0);
    }
    __builtin_amdgcn_s_setprio(0);

    __syncthreads();  // all waves done with buf; prefetch into buf^1 drained here
  }

  // l for own half, q=l31: own lane covers kv-slots with bit2==hi; partner lane the rest
  float lt = lacc + __shfl_xor(lacc, 32);

  // combine kv-halves across partner waves via dead K/V buffers (r7-verified epilogue)
  float* Cg = (qg < 2) ? ((float*)&Kb[0][0] + qg * 2048)
                       : ((float*)&Vb[0][0] + (qg - 2) * 2048);
  if (h == 1) {
#pragma unroll
    for (int r = 0; r < 16; ++r) {
      int ro = (r & 3) + 8 * (r >> 2) + 4 * hi;
      Cg[ro * 64 + l31] = oa0[r];
      Cg[ro * 64 + 32 + l31] = oa1[r];
    }
    if (hi == 0) Lsum[qg][l31] = lt;
  }
  __syncthreads();
  if (h == 0) {
    float rlq = 1.0f / (lt + Lsum[qg][l31]);
    const int b = hl / NH, hh = hl % NH;
    bf16* outp = ctx + ((size_t)b * SQ + q0 + qg * 32) * H + hh * HD;
#pragma unroll
    for (int r = 0; r < 16; ++r) {
      int qo = (r & 3) + 8 * (r >> 2) + 4 * hi;
      float rv = __shfl(rlq, qo);
      float v0 = oa0[r] + Cg[qo * 64 + l31];
      float v1 = oa1[r] + Cg[qo * 64 + 32 + l31];
      bf16* rowp = outp + (size_t)qo * H;
      rowp[l31]      = __float2bfloat16(v0 * rv);
      rowp[32 + l31] = __float2bfloat16(v1 * rv);
    }
  }
}

// ---------------- residual + post-LN: o = res + LN(x)*g + beta (x,res bf16; 192 thr) ----------------
__global__ __launch_bounds__(192) void ln_res(
    const bf16* __restrict__ x, const bf16* __restrict__ res,
    const float* __restrict__ g, const float* __restrict__ beta,
    float* __restrict__ o32, bf16* __restrict__ ob) {
  const int row = blockIdx.x;
  const int t = threadIdx.x;
  float v[4];
  float s = 0.f, s2 = 0.f;
  ushort4 xv = ((const ushort4*)(x + (size_t)row * H))[t];
  v[0] = bf2f(xv.x); v[1] = bf2f(xv.y); v[2] = bf2f(xv.z); v[3] = bf2f(xv.w);
#pragma unroll
  for (int k = 0; k < 4; ++k) { s += v[k]; s2 += v[k] * v[k]; }
#pragma unroll
  for (int off = 32; off > 0; off >>= 1) {
    s += __shfl_down(s, off);
    s2 += __shfl_down(s2, off);
  }
  __shared__ float red[8];
  if ((t & 63) == 0) { red[t >> 6] = s; red[4 + (t >> 6)] = s2; }
  __syncthreads();
  float st = red[0] + red[1] + red[2];
  float s2t = red[4] + red[5] + red[6];
  float mean = st * (1.f / 768.f);
  float var = s2t * (1.f / 768.f) - mean * mean;
  float rs = rsqrtf(var + 1e-5f);
  {
    ushort4 rv4 = ((const ushort4*)(res + (size_t)row * H))[t];
    float4 gv = ((const float4*)g)[t];
    float4 bv = ((const float4*)beta)[t];
    float4 o;
    o.x = bf2f(rv4.x) + (v[0] - mean) * rs * gv.x + bv.x;
    o.y = bf2f(rv4.y) + (v[1] - mean) * rs * gv.y + bv.y;
    o.z = bf2f(rv4.z) + (v[2] - mean) * rs * gv.z + bv.z;
    o.w = bf2f(rv4.w) + (v[3] - mean) * rs * gv.w + bv.w;
    if (o32) ((float4*)(o32 + (size_t)row * H))[t] = o;
    if (ob) {
      uint2 q;
      q.x = cvtpk(o.x, o.y);
      q.y = cvtpk(o.z, o.w);
      ((uint2*)(ob + (size_t)row * H))[t] = q;
    }
  }
}

extern "C" void kernel_launch(void* const* d_in, const int* in_sizes, int n_in,
                              void* d_out, int out_size, void* d_ws, size_t ws_size,
                              hipStream_t stream) {
  const float* freq  = (const float*)d_in[0];
  const float* image = (const float*)d_in[1];
  const float* Wq = (const float*)d_in[2];
  const float* bq = (const float*)d_in[3];
  const float* Wk = (const float*)d_in[4];
  const float* bk = (const float*)d_in[5];
  const float* Wv = (const float*)d_in[6];
  const float* bv = (const float*)d_in[7];
  const float* g1 = (const float*)d_in[8];
  const float* be1 = (const float*)d_in[9];
  const float* g2 = (const float*)d_in[10];
  const float* be2 = (const float*)d_in[11];
  const float* W1 = (const float*)d_in[12];
  const float* b1 = (const float*)d_in[13];
  const float* W2 = (const float*)d_in[14];
  const float* b2 = (const float*)d_in[15];

  const int Bc = in_sizes[0] / (SQ * H);  // 8
  const int M = Bc * SQ;                  // 8192

  char* p = (char*)d_ws;
  bf16* W1T = (bf16*)p;  p += (size_t)FF * H * 2;
  bf16* W2T = (bf16*)p;  p += (size_t)H * FF * 2;
  bf16* ctxb = (bf16*)p; p += (size_t)M * H * 2;   // attn out (bf16); reused for mlp2 out
  bf16* hb = (bf16*)p;   p += (size_t)M * H * 2;   // h = freq + LN(ctx) in bf16 (residual + MLP1 A)
  char* U = p;  // union region
  bf16* freqb = (bf16*)U;
  bf16* imageb = (bf16*)(U + (size_t)M * H * 2);
  bf16* WTq   = (bf16*)(U + (size_t)2 * M * H * 2);
  bf16* WTkv  = (bf16*)(U + (size_t)2 * M * H * 2 + (size_t)H * H * 2);
  bf16* Qb    = (bf16*)(U + (size_t)2 * M * H * 2 + (size_t)3 * H * H * 2);
  bf16* Kbuf  = (bf16*)((char*)Qb + (size_t)M * H * 2);
  bf16* VTb   = (bf16*)((char*)Kbuf + (size_t)M * H * 2);
  bf16* mlp1  = (bf16*)U;    // reused after attention+ln1 consumed freqb/Q/K/VT
  bf16* mlp2b = ctxb;        // reused after first ln_res consumed ctxb

  // fused pre-pass: c1 blocks per cvt, then 3x576 + 2x2304 transpose tiles
  int c1 = M * H / 1024;
  int nprep = 2 * c1 + 3 * ((H / 32) * (H / 32)) + (FF / 32) * (H / 32) + (H / 32) * (FF / 32);
  prep<<<nprep, 256, 0, stream>>>(freq, image, freqb, imageb,
                                  Wq, Wk, Wv, W1, W2,
                                  WTq, WTkv, WTkv + (size_t)H * H, W1T, W2T, c1);

  // fused QKV projection: 768 KV-blocks (BN=128 over N=1536) + 384 Q-blocks (BN=128 over N=768)
  int nqkv = (M / 128) * (2 * H / 128) + (M / 128) * (H / 128);  // 1152, %8==0
  gemm_bt<4, 128, 512><<<nqkv, 512, 0, stream>>>(imageb, WTkv, bk, bv, Kbuf, VTb, M, 2 * H, H,
                                                 freqb, WTq, bq, Qb);
  int nblk = Bc * NH * (SQ / 128);
  attn_fwd<<<nblk, 512, 0, stream>>>(Qb, Kbuf, VTb, ctxb, nblk);
  ln_res<<<M, 192, 0, stream>>>(ctxb, freqb, g1, be1, nullptr, hb);
  gemm_bt<2, 128, 512><<<(M / 128) * (FF / 128), 512, 0, stream>>>(hb, W1T, b1, nullptr, mlp1, nullptr,
                                                                   M, FF, H, nullptr, nullptr, nullptr, nullptr);
  gemm_bt<3, 64, 512><<<(M / 128) * (H / 64), 512, 0, stream>>>(mlp1, W2T, b2, nullptr, mlp2b, nullptr,
                                                                M, H, FF, nullptr, nullptr, nullptr, nullptr);
  ln_res<<<M, 192, 0, stream>>>(mlp2b, hb, g2, be2, (float*)d_out, nullptr);
}

// Round 18
// 215.278 us; speedup vs baseline: 1.0367x; 1.0060x over previous
//
#include <hip/hip_runtime.h>
#include <hip/hip_bf16.h>

#define H 768
#define NH 12
#define HD 64
#define FF 3072
#define SQ 1024
#define SKV 1024

typedef __hip_bfloat16 bf16;
typedef __attribute__((ext_vector_type(8))) short short8;   // bf16x8 fragment (guide §3)
typedef __attribute__((ext_vector_type(4))) float f32x4;
typedef __attribute__((ext_vector_type(16))) float f32x16;

__device__ inline void gload16(const void* g, void* l) {
  __builtin_amdgcn_global_load_lds((const __attribute__((address_space(1))) void*)g,
                                   (__attribute__((address_space(3))) void*)l, 16, 0, 0);
}

__device__ inline float bf2f(unsigned short u) {
  unsigned int x = ((unsigned int)u) << 16;
  return __builtin_bit_cast(float, x);
}

// packed bf16 pair: lo -> bits[15:0], hi -> bits[31:16]
__device__ inline unsigned int cvtpk(float lo, float hi) {
  unsigned int r;
  asm("v_cvt_pk_bf16_f32 %0, %1, %2" : "=v"(r) : "v"(lo), "v"(hi));
  return r;
}

// ---------------- fused pre-pass: 2x cvt_bf16 + 5x transpose-convert in one launch ----------------
__device__ inline void cvt_body(const float* __restrict__ src, bf16* __restrict__ dst, int blk) {
  int i = blk * 256 + threadIdx.x;
  float4 v = ((const float4*)src)[i];
  union { unsigned short u[4]; uint2 q; } o;
  bf16 t0 = __float2bfloat16(v.x); o.u[0] = *(unsigned short*)&t0;
  bf16 t1 = __float2bfloat16(v.y); o.u[1] = *(unsigned short*)&t1;
  bf16 t2 = __float2bfloat16(v.z); o.u[2] = *(unsigned short*)&t2;
  bf16 t3 = __float2bfloat16(v.w); o.u[3] = *(unsigned short*)&t3;
  ((uint2*)dst)[i] = o.q;
}

__device__ inline void trans_body(const float* __restrict__ src, bf16* __restrict__ dst,
                                  int Kd, int Nd, int blk, float* tile /*32*33*/) {
  int ntx = Nd >> 5;
  int n0 = (blk % ntx) << 5, k0 = (blk / ntx) << 5;
  int tx = threadIdx.x & 31, ty = threadIdx.x >> 5;  // 32 x 8
#pragma unroll
  for (int i = 0; i < 4; ++i)
    tile[(ty + i * 8) * 33 + tx] = src[(size_t)(k0 + ty + i * 8) * Nd + n0 + tx];
  __syncthreads();
#pragma unroll
  for (int i = 0; i < 4; ++i)
    dst[(size_t)(n0 + ty + i * 8) * Kd + k0 + tx] = __float2bfloat16(tile[tx * 33 + ty + i * 8]);
}

__global__ __launch_bounds__(256) void prep(
    const float* freq, const float* image, bf16* freqb, bf16* imageb,
    const float* Wq, const float* Wk, const float* Wv, const float* W1, const float* W2,
    bf16* WTq, bf16* WTk, bf16* WTv, bf16* W1T, bf16* W2T, int c1) {
  __shared__ float tile[32 * 33];
  int b = blockIdx.x;
  if (b < c1) { cvt_body(freq, freqb, b); return; }
  b -= c1;
  if (b < c1) { cvt_body(image, imageb, b); return; }
  b -= c1;
  const int TQ = (H / 32) * (H / 32);        // 576
  const int T1 = (FF / 32) * (H / 32);       // 2304
  if (b < TQ)            { trans_body(Wq, WTq, H, H, b, tile); return; }
  b -= TQ;
  if (b < TQ)            { trans_body(Wk, WTk, H, H, b, tile); return; }
  b -= TQ;
  if (b < TQ)            { trans_body(Wv, WTv, H, H, b, tile); return; }
  b -= TQ;
  if (b < T1)            { trans_body(W1, W1T, H, FF, b, tile); return; }
  b -= T1;
  trans_body(W2, W2T, FF, H, b, tile);
}

// ---------------- GEMM: C[M,N] = A[M,K] * BT[N,K]^T, 128xBN tile, BK=64 ----------------
// TH=512: 8 waves, wave grid 4x2 (wave tile 32 x BN/2).
// EPI 2: MLP1 -> out0 bf16 [M][N], relu(x+bias0)
// EPI 3: MLP2 -> out0 bf16 [M][N], x+bias0
// EPI 4: fused QKV. Blocks [0,nkv): KV-proj (K out0, V^T out1 packed). Blocks [nkv,..): Q-proj.
template <int EPI, int BN, int TH>
__global__ __launch_bounds__(TH) void gemm_bt(
    const bf16* __restrict__ A, const bf16* __restrict__ BT,
    const float* __restrict__ bias0, const float* __restrict__ bias1,
    void* __restrict__ out0, void* __restrict__ out1, int M, int N, int K,
    const bf16* __restrict__ Aq, const bf16* __restrict__ BTq,
    const float* __restrict__ biasq, void* __restrict__ outq) {
  constexpr int JF = BN / 32;        // col-frags per wave (wc spans BN/2)
  constexpr int MI = (TH == 512) ? 2 : 4;     // m-frags per wave
  constexpr int WROW = (TH == 512) ? 32 : 64; // wave row span
  constexpr int AI = 1024 / TH;      // A-stage iterations (1024 slots of 16B)
  constexpr int BI = BN * 8 / TH;    // B-stage iterations
  __shared__ __align__(16) bf16 lA[128 * 64];
  __shared__ __align__(16) bf16 lB[BN * 64];
  const int t = threadIdx.x;
  const int lane = t & 63, w = t >> 6;
  const int wr = w >> 1, wc = w & 1;
  const int nwg = gridDim.x;
  int bid = blockIdx.x;
  int logical = ((nwg & 7) == 0) ? ((bid & 7) * (nwg >> 3) + (bid >> 3)) : bid;

  bool isq = false;
  int lg = logical;
  const bf16* Ause = A;
  const bf16* BTuse = BT;
  int nt = N / BN;
  if (EPI == 4) {
    const int nkv = (M >> 7) * (2 * H / BN);   // 768
    if (logical >= nkv) {
      isq = true; lg = logical - nkv;
      Ause = Aq; BTuse = BTq; nt = H / BN;
    }
  }
  const int m0 = (lg / nt) << 7;
  const int n0 = (lg % nt) * BN;

  const f32x4 fz = {0.f, 0.f, 0.f, 0.f};
  f32x4 acc[MI][JF];
#pragma unroll
  for (int i = 0; i < MI; ++i)
#pragma unroll
    for (int j = 0; j < JF; ++j) acc[i][j] = fz;

  for (int kt = 0; kt < K; kt += 64) {
    // A tile: 1024 slots of 16B
#pragma unroll
    for (int i = 0; i < AI; ++i) {
      int idx = i * TH + t;
      int row = idx >> 3;
      int chunk = (idx & 7) ^ (row & 7);
      gload16(Ause + (size_t)(m0 + row) * K + kt + chunk * 8, lA + (size_t)(i * TH + w * 64) * 8);
    }
    // B tile: BN*8 slots
#pragma unroll
    for (int i = 0; i < BI; ++i) {
      int idx = i * TH + t;
      int row = idx >> 3;
      int chunk = (idx & 7) ^ (row & 7);
      gload16(BTuse + (size_t)(n0 + row) * K + kt + chunk * 8, lB + (size_t)(i * TH + w * 64) * 8);
    }
    __syncthreads();

    short8 af[2][MI], bfv[2][JF];
#pragma unroll
    for (int s = 0; s < 2; ++s) {
#pragma unroll
      for (int i = 0; i < MI; ++i) {
        int ra = wr * WROW + i * 16 + (lane & 15);
        int ca = (s * 4 + (lane >> 4)) ^ (ra & 7);
        af[s][i] = *(const short8*)&lA[ra * 64 + ca * 8];
      }
#pragma unroll
      for (int j = 0; j < JF; ++j) {
        int rb = wc * (BN / 2) + j * 16 + (lane & 15);
        int cb = (s * 4 + (lane >> 4)) ^ (rb & 7);
        bfv[s][j] = *(const short8*)&lB[rb * 64 + cb * 8];
      }
    }
#pragma unroll
    for (int s = 0; s < 2; ++s)
#pragma unroll
      for (int i = 0; i < MI; ++i)
#pragma unroll
        for (int j = 0; j < JF; ++j)
          acc[i][j] = __builtin_amdgcn_mfma_f32_16x16x32_bf16(af[s][i], bfv[s][j], acc[i][j], 0, 0, 0);
    __syncthreads();
  }

  // epilogue (C/D layout: row=(lane>>4)*4+r, col=lane&15 — m89/m91 verified)
#pragma unroll
  for (int i = 0; i < MI; ++i) {
    int mbase = m0 + wr * WROW + i * 16 + ((lane >> 4) << 2);
    int mb = mbase & 1023, bidx = mbase >> 10;
#pragma unroll
    for (int j = 0; j < JF; ++j) {
      int n = n0 + wc * (BN / 2) + j * 16 + (lane & 15);
      if (EPI == 4) {
        if (isq) {
          int hlin = bidx * NH + (n >> 6);
#pragma unroll
          for (int r = 0; r < 4; ++r) {
            float v = (acc[i][j][r] + biasq[n]) * 0.180336880f;  // 0.125*log2e folded
            ((bf16*)outq)[((size_t)hlin * SQ + (mb + r)) * HD + (n & 63)] = __float2bfloat16(v);
          }
        } else {
          int sel = (n >= H);
          int nn = n - (sel ? H : 0);
          int hlin = bidx * NH + (nn >> 6);
          float bsv = (sel ? bias1 : bias0)[nn];
          float v0 = acc[i][j][0] + bsv, v1 = acc[i][j][1] + bsv;
          float v2 = acc[i][j][2] + bsv, v3 = acc[i][j][3] + bsv;
          if (!sel) {
            bf16* kp = (bf16*)out0 + ((size_t)hlin * SKV + mb) * HD + (nn & 63);
            kp[0 * HD] = __float2bfloat16(v0);
            kp[1 * HD] = __float2bfloat16(v1);
            kp[2 * HD] = __float2bfloat16(v2);
            kp[3 * HD] = __float2bfloat16(v3);
          } else {
            // V^T: 4 m-contiguous values -> one 8B store
            uint2 u;
            u.x = cvtpk(v0, v1);
            u.y = cvtpk(v2, v3);
            *(uint2*)((bf16*)out1 + ((size_t)hlin * HD + (nn & 63)) * SKV + mb) = u;
          }
        }
      } else {
#pragma unroll
        for (int r = 0; r < 4; ++r) {
          int m = mbase + r;
          float v = acc[i][j][r] + bias0[n];
          if (EPI == 2) v = fmaxf(v, 0.f);
          ((bf16*)out0)[(size_t)m * N + n] = __float2bfloat16(v);
        }
      }
    }
  }
}

// ---------------- flash attention: 32x32 MFMA, in-register softmax, q-group x kv-half waves ----------
// 1 block = (head, 128 q-rows), 8 waves = 4 q-groups x 2 kv-halves. Q pre-scaled by 0.125*log2e.
// No-max softmax: P = exp2(S) (scores O(3) in log2 domain; constant cancels in O/l).
// Swapped QK^T (r6-verified): sc = mfma(K_rows, Q) -> lane holds P[q=l31][16 kv of its half].
// Each wave covers kv = 32h..32h+31 of every tile: half the K/V fragment reads of full-kv waves;
// P fully in-register via cvtpk+permlane32_swap (r6 recipe, pa k4global in {2h,2h+1});
// l accumulated in-register (no ones-MFMA). Partner waves (h=0/1) combine O and l through the
// dead K/V LDS buffers after the loop (r7-verified epilogue). Q loaded direct from global.
__global__ __launch_bounds__(512) void attn_fwd(
    const bf16* __restrict__ Q,   // [B*NH][SQ][HD] (pre-scaled)
    const bf16* __restrict__ Kg_, // [B*NH][SKV][HD]
    const bf16* __restrict__ VT,  // [B*NH][HD][SKV]
    bf16* __restrict__ ctx, int nblk) {  // [B][SQ][H] bf16
  __shared__ __align__(16) bf16 Kb[2][64 * 64];  // 8KB per buf
  __shared__ __align__(16) bf16 Vb[2][64 * 64];
  __shared__ float Lsum[4][32];

  const int t = threadIdx.x, lane = t & 63, w = t >> 6;
  const int hi = lane >> 5, l31 = lane & 31;
  const int qg = w >> 1, h = w & 1;   // q-group 0..3, kv-half 0..1
  int bid = blockIdx.x;
  int logical = ((nblk & 7) == 0) ? (bid & 7) * (nblk >> 3) + (bid >> 3) : bid;
  const int hl = logical >> 3;          // SQ/128 = 8 q-blocks per head
  const int q0 = (logical & 7) << 7;
  const bf16* Qg = Q + ((size_t)hl * SQ + q0) * HD;
  const bf16* Kg = Kg_ + (size_t)hl * SKV * HD;
  const bf16* Vg = VT + (size_t)hl * HD * SKV;

  // Q fragments direct from global (B-operand of swapped QK^T): row q = qg*32+l31, k=d
  short8 aq[4];
  {
    const bf16* qp = Qg + (size_t)(qg * 32 + l31) * HD;
#pragma unroll
    for (int ks = 0; ks < 4; ++ks)
      aq[ks] = *(const short8*)(qp + (ks * 2 + hi) * 8);
  }

  // prologue: stage K0, V0 (512 slots each, 1 per thread; swizzled source / linear dest, G21)
  {
    int row = t >> 3, chunk = (t & 7) ^ (row & 7);
    gload16(Kg + (size_t)row * HD + chunk * 8, (char*)&Kb[0][0] + (size_t)t * 16);
    gload16(Vg + (size_t)row * SKV + chunk * 8, (char*)&Vb[0][0] + (size_t)t * 16);
  }
  __syncthreads();

  f32x16 oa0, oa1;
#pragma unroll
  for (int r = 0; r < 16; ++r) { oa0[r] = 0.f; oa1[r] = 0.f; }
  float lacc = 0.f;

#pragma unroll 2
  for (int i = 0; i < 16; ++i) {
    const int buf = i & 1;
    if (i < 15) {  // prefetch next K/V tile into buf^1 (in flight across the compute)
      int kvn = (i + 1) << 6;
      int row = t >> 3, chunk = (t & 7) ^ (row & 7);
      gload16(Kg + (size_t)(kvn + row) * HD + chunk * 8, (char*)&Kb[buf ^ 1][0] + (size_t)t * 16);
      gload16(Vg + (size_t)row * SKV + kvn + chunk * 8, (char*)&Vb[buf ^ 1][0] + (size_t)t * 16);
    }

    // S^T half = mfma(K[kv=32h..32h+31], Q): sc[r] = S[q=l31][kv=32h+(r&3)+8*(r>>2)+4*hi]
    f32x16 sc;
#pragma unroll
    for (int r = 0; r < 16; ++r) sc[r] = 0.f;
    __builtin_amdgcn_s_setprio(1);
#pragma unroll
    for (int ks = 0; ks < 4; ++ks) {
      int c0 = ks * 2 + hi;
      int r0 = h * 32 + l31;
      short8 kf = *(const short8*)&Kb[buf][r0 * 64 + ((c0 ^ (r0 & 7)) * 8)];
      sc = __builtin_amdgcn_mfma_f32_32x32x16_bf16(kf, aq[ks], sc, 0, 0, 0);
    }
    __builtin_amdgcn_s_setprio(0);

    // P = exp2(S) in-register; accumulate partial l
#pragma unroll
    for (int r = 0; r < 16; ++r) { sc[r] = exp2f(sc[r]); lacc += sc[r]; }

    // PA fragments for own kv-half: pa[k4l], k4global = 2h + k4l (r6-verified recipe)
    short8 pa[2];
#pragma unroll
    for (int k4 = 0; k4 < 2; ++k4) {
      const int base = k4 * 8;
      unsigned int p0 = cvtpk(sc[base + 0], sc[base + 1]);
      unsigned int p1 = cvtpk(sc[base + 2], sc[base + 3]);
      unsigned int qq0 = cvtpk(sc[base + 4], sc[base + 5]);
      unsigned int qq1 = cvtpk(sc[base + 6], sc[base + 7]);
      asm volatile("v_permlane32_swap_b32 %0, %1" : "+v"(p0), "+v"(qq0));
      asm volatile("v_permlane32_swap_b32 %0, %1" : "+v"(p1), "+v"(qq1));
      union { unsigned int u[4]; short8 s8; } pu;
      pu.u[0] = p0; pu.u[1] = p1; pu.u[2] = qq0; pu.u[3] = qq1;
      pa[k4] = pu.s8;
    }

    // O += P V over own kv-half (V^T tile: rows d, cols kv; cc = 4h + 2*k4l + hi)
    __builtin_amdgcn_s_setprio(1);
#pragma unroll
    for (int k4 = 0; k4 < 2; ++k4) {
      int cc = 4 * h + k4 * 2 + hi;
      int r0 = l31;
      short8 vf0 = *(const short8*)&Vb[buf][r0 * 64 + ((cc ^ (r0 & 7)) * 8)];
      oa0 = __builtin_amdgcn_mfma_f32_32x32x16_bf16(pa[k4], vf0, oa0, 0, 0, 0);
      int r1 = 32 + l31;
      short8 vf1 = *(const short8*)&Vb[buf][r1 * 64 + ((cc ^ (r1 & 7)) * 8)];
      oa1 = __builtin_amdgcn_mfma_f32_32x32x16_bf16(pa[k4], vf1, oa1, 0, 0, 0);
    }
    __builtin_amdgcn_s_setprio(0);

    __syncthreads();  // all waves done with buf; prefetch into buf^1 drained here
  }

  // l for own half, q=l31: own lane covers kv-slots with bit2==hi; partner lane the rest
  float lt = lacc + __shfl_xor(lacc, 32);

  // combine kv-halves across partner waves via dead K/V buffers (r7-verified epilogue)
  float* Cg = (qg < 2) ? ((float*)&Kb[0][0] + qg * 2048)
                       : ((float*)&Vb[0][0] + (qg - 2) * 2048);
  if (h == 1) {
#pragma unroll
    for (int r = 0; r < 16; ++r) {
      int ro = (r & 3) + 8 * (r >> 2) + 4 * hi;
      Cg[ro * 64 + l31] = oa0[r];
      Cg[ro * 64 + 32 + l31] = oa1[r];
    }
    if (hi == 0) Lsum[qg][l31] = lt;
  }
  __syncthreads();
  if (h == 0) {
    float rlq = 1.0f / (lt + Lsum[qg][l31]);
    const int b = hl / NH, hh = hl % NH;
    bf16* outp = ctx + ((size_t)b * SQ + q0 + qg * 32) * H + hh * HD;
#pragma unroll
    for (int r = 0; r < 16; ++r) {
      int qo = (r & 3) + 8 * (r >> 2) + 4 * hi;
      float rv = __shfl(rlq, qo);
      float v0 = oa0[r] + Cg[qo * 64 + l31];
      float v1 = oa1[r] + Cg[qo * 64 + 32 + l31];
      bf16* rowp = outp + (size_t)qo * H;
      rowp[l31]      = __float2bfloat16(v0 * rv);
      rowp[32 + l31] = __float2bfloat16(v1 * rv);
    }
  }
}

// ---------------- residual + post-LN: o = res + LN(x)*g + beta (x,res bf16; 192 thr) ----------------
__global__ __launch_bounds__(192) void ln_res(
    const bf16* __restrict__ x, const bf16* __restrict__ res,
    const float* __restrict__ g, const float* __restrict__ beta,
    float* __restrict__ o32, bf16* __restrict__ ob) {
  const int row = blockIdx.x;
  const int t = threadIdx.x;
  float v[4];
  float s = 0.f, s2 = 0.f;
  ushort4 xv = ((const ushort4*)(x + (size_t)row * H))[t];
  v[0] = bf2f(xv.x); v[1] = bf2f(xv.y); v[2] = bf2f(xv.z); v[3] = bf2f(xv.w);
#pragma unroll
  for (int k = 0; k < 4; ++k) { s += v[k]; s2 += v[k] * v[k]; }
#pragma unroll
  for (int off = 32; off > 0; off >>= 1) {
    s += __shfl_down(s, off);
    s2 += __shfl_down(s2, off);
  }
  __shared__ float red[8];
  if ((t & 63) == 0) { red[t >> 6] = s; red[4 + (t >> 6)] = s2; }
  __syncthreads();
  float st = red[0] + red[1] + red[2];
  float s2t = red[4] + red[5] + red[6];
  float mean = st * (1.f / 768.f);
  float var = s2t * (1.f / 768.f) - mean * mean;
  float rs = rsqrtf(var + 1e-5f);
  {
    ushort4 rv4 = ((const ushort4*)(res + (size_t)row * H))[t];
    float4 gv = ((const float4*)g)[t];
    float4 bv = ((const float4*)beta)[t];
    float4 o;
    o.x = bf2f(rv4.x) + (v[0] - mean) * rs * gv.x + bv.x;
    o.y = bf2f(rv4.y) + (v[1] - mean) * rs * gv.y + bv.y;
    o.z = bf2f(rv4.z) + (v[2] - mean) * rs * gv.z + bv.z;
    o.w = bf2f(rv4.w) + (v[3] - mean) * rs * gv.w + bv.w;
    if (o32) ((float4*)(o32 + (size_t)row * H))[t] = o;
    if (ob) {
      uint2 q;
      q.x = cvtpk(o.x, o.y);
      q.y = cvtpk(o.z, o.w);
      ((uint2*)(ob + (size_t)row * H))[t] = q;
    }
  }
}

extern "C" void kernel_launch(void* const* d_in, const int* in_sizes, int n_in,
                              void* d_out, int out_size, void* d_ws, size_t ws_size,
                              hipStream_t stream) {
  const float* freq  = (const float*)d_in[0];
  const float* image = (const float*)d_in[1];
  const float* Wq = (const float*)d_in[2];
  const float* bq = (const float*)d_in[3];
  const float* Wk = (const float*)d_in[4];
  const float* bk = (const float*)d_in[5];
  const float* Wv = (const float*)d_in[6];
  const float* bv = (const float*)d_in[7];
  const float* g1 = (const float*)d_in[8];
  const float* be1 = (const float*)d_in[9];
  const float* g2 = (const float*)d_in[10];
  const float* be2 = (const float*)d_in[11];
  const float* W1 = (const float*)d_in[12];
  const float* b1 = (const float*)d_in[13];
  const float* W2 = (const float*)d_in[14];
  const float* b2 = (const float*)d_in[15];

  const int Bc = in_sizes[0] / (SQ * H);  // 8
  const int M = Bc * SQ;                  // 8192

  char* p = (char*)d_ws;
  bf16* W1T = (bf16*)p;  p += (size_t)FF * H * 2;
  bf16* W2T = (bf16*)p;  p += (size_t)H * FF * 2;
  bf16* ctxb = (bf16*)p; p += (size_t)M * H * 2;   // attn out (bf16); reused for mlp2 out
  bf16* hb = (bf16*)p;   p += (size_t)M * H * 2;   // h = freq + LN(ctx) in bf16 (residual + MLP1 A)
  char* U = p;  // union region
  bf16* freqb = (bf16*)U;
  bf16* imageb = (bf16*)(U + (size_t)M * H * 2);
  bf16* WTq   = (bf16*)(U + (size_t)2 * M * H * 2);
  bf16* WTkv  = (bf16*)(U + (size_t)2 * M * H * 2 + (size_t)H * H * 2);
  bf16* Qb    = (bf16*)(U + (size_t)2 * M * H * 2 + (size_t)3 * H * H * 2);
  bf16* Kbuf  = (bf16*)((char*)Qb + (size_t)M * H * 2);
  bf16* VTb   = (bf16*)((char*)Kbuf + (size_t)M * H * 2);
  bf16* mlp1  = (bf16*)U;    // reused after attention+ln1 consumed freqb/Q/K/VT
  bf16* mlp2b = ctxb;        // reused after first ln_res consumed ctxb

  // fused pre-pass: c1 blocks per cvt, then 3x576 + 2x2304 transpose tiles
  int c1 = M * H / 1024;
  int nprep = 2 * c1 + 3 * ((H / 32) * (H / 32)) + (FF / 32) * (H / 32) + (H / 32) * (FF / 32);
  prep<<<nprep, 256, 0, stream>>>(freq, image, freqb, imageb,
                                  Wq, Wk, Wv, W1, W2,
                                  WTq, WTkv, WTkv + (size_t)H * H, W1T, W2T, c1);

  // fused QKV projection: 768 KV-blocks (BN=128 over N=1536) + 384 Q-blocks (BN=128 over N=768)
  int nqkv = (M / 128) * (2 * H / 128) + (M / 128) * (H / 128);  // 1152, %8==0
  gemm_bt<4, 128, 512><<<nqkv, 512, 0, stream>>>(imageb, WTkv, bk, bv, Kbuf, VTb, M, 2 * H, H,
                                                 freqb, WTq, bq, Qb);
  int nblk = Bc * NH * (SQ / 128);
  attn_fwd<<<nblk, 512, 0, stream>>>(Qb, Kbuf, VTb, ctxb, nblk);
  ln_res<<<M, 192, 0, stream>>>(ctxb, freqb, g1, be1, nullptr, hb);
  // MLP1: BN=256 (wave tile 32x128, 32 MFMA : 20 ds_read per K-step) — 768 blocks, LDS 48KB
  gemm_bt<2, 256, 512><<<(M / 128) * (FF / 256), 512, 0, stream>>>(hb, W1T, b1, nullptr, mlp1, nullptr,
                                                                   M, FF, H, nullptr, nullptr, nullptr, nullptr);
  gemm_bt<3, 64, 512><<<(M / 128) * (H / 64), 512, 0, stream>>>(mlp1, W2T, b2, nullptr, mlp2b, nullptr,
                                                                M, H, FF, nullptr, nullptr, nullptr, nullptr);
  ln_res<<<M, 192, 0, stream>>>(mlp2b, hb, g2, be2, (float*)d_out, nullptr);
}